// Round 2
// baseline (30363.174 us; speedup 1.0000x reference)
//
#include <hip/hip_runtime.h>
#include <hip/hip_bf16.h>

typedef __hip_bfloat16 bf16;

#define NP0 50000
#define NP1 20000
#define NP2 8000
#define NP3 3200
#define NP4 1300

#define TN 64
#define TCO 64
#define TCI 32

static __device__ __forceinline__ float b2f(bf16 v) { return __bfloat162float(v); }

// Load element i of buffer P which is bf16 if isbf else fp32.
static __device__ __forceinline__ float pload(const void* P, int isbf, size_t i) {
  return isbf ? b2f(((const bf16*)P)[i]) : ((const float*)P)[i];
}

// Decide whether the float payloads are bf16 (flag=1) or fp32 (flag=0).
// Even-indexed uint16 halves of a bf16 buffer are real bf16 values (|x|<~10);
// for an fp32 buffer they are random mantissa bits -> huge/NaN with prob ~1.
__global__ void k_sniff(const void* __restrict__ xraw, int* __restrict__ flagp) {
  __shared__ float smax[256];
  const unsigned short* u = (const unsigned short*)xraw;
  float m = 0.f;
  for (int i = threadIdx.x; i < 2048; i += 256) {
    unsigned int w = ((unsigned int)u[2 * i]) << 16;
    float v = __uint_as_float(w);
    if (isnan(v) || isinf(v)) m = 1e30f;
    else m = fmaxf(m, fabsf(v));
  }
  smax[threadIdx.x] = m;
  __syncthreads();
  for (int s = 128; s > 0; s >>= 1) {
    if (threadIdx.x < s) smax[threadIdx.x] = fmaxf(smax[threadIdx.x], smax[threadIdx.x + s]);
    __syncthreads();
  }
  if (threadIdx.x == 0) *flagp = (smax[0] < 1e4f) ? 1 : 0;
}

// Generic gather-GEMM: Y[n,co] = sum_k sum_ci X[nbr[n,k], ci] * W[k,ci,co]
// nbr==null -> identity rows (dense linear). W/bias live in params (offset),
// dtype per flag. out_dyn: 0 -> fp32 ws buffer, 1 -> harness dtype per flag.
__global__ __launch_bounds__(256) void k_conv(
    const float* __restrict__ X, const int* __restrict__ nbr,
    const void* __restrict__ P, size_t wofs, void* __restrict__ Yd, int out_dyn,
    size_t bofs, int relu, int N, int K, int CI, int CO,
    const int* __restrict__ flagp)
{
  __shared__ float xs[TN * (TCI + 1)];
  __shared__ float wsm[TCI * TCO];
  __shared__ int idxs[TN];
  const int wbf = *flagp;
  const int t = threadIdx.x;
  const int row0 = blockIdx.x * TN;
  const int co0 = blockIdx.y * TCO;
  const int ty = t >> 4, tx = t & 15;
  float acc[4][4] = {};
  for (int k = 0; k < K; ++k) {
    if (t < TN) {
      int r = row0 + t;
      idxs[t] = (r < N) ? (nbr ? nbr[(size_t)r * K + k] : r) : 0;
    }
    const size_t wk = wofs + (size_t)k * CI * CO;
    for (int cb = 0; cb < CI; cb += TCI) {
      __syncthreads();
#pragma unroll
      for (int i = 0; i < 8; ++i) {
        int e = t + i * 256; int r = e >> 5, cc = e & 31; int ci = cb + cc;
        float v = 0.f;
        if (ci < CI) v = X[(size_t)idxs[r] * CI + ci];
        xs[r * (TCI + 1) + cc] = v;
      }
#pragma unroll
      for (int i = 0; i < 8; ++i) {
        int e = t + i * 256; int cc = e >> 6, j = e & 63;
        int ci = cb + cc, co = co0 + j;
        float v = 0.f;
        if (ci < CI && co < CO) v = pload(P, wbf, wk + (size_t)ci * CO + co);
        wsm[cc * TCO + j] = v;
      }
      __syncthreads();
#pragma unroll
      for (int cc = 0; cc < TCI; ++cc) {
        const float4 w4 = *(const float4*)&wsm[cc * TCO + (tx << 2)];
#pragma unroll
        for (int i = 0; i < 4; ++i) {
          float xv = xs[(ty * 4 + i) * (TCI + 1) + cc];
          acc[i][0] += xv * w4.x; acc[i][1] += xv * w4.y;
          acc[i][2] += xv * w4.z; acc[i][3] += xv * w4.w;
        }
      }
    }
  }
#pragma unroll
  for (int i = 0; i < 4; ++i) {
    int r = row0 + ty * 4 + i;
    if (r >= N) continue;
#pragma unroll
    for (int j = 0; j < 4; ++j) {
      int co = co0 + (tx << 2) + j;
      if (co >= CO) continue;
      float v = acc[i][j];
      if (bofs != (size_t)-1) v += pload(P, wbf, bofs + co);
      if (relu) v = fmaxf(v, 0.f);
      size_t oi = (size_t)r * CO + co;
      if (out_dyn) {
        if (wbf) ((bf16*)Yd)[oi] = __float2bfloat16(v);
        else ((float*)Yd)[oi] = v;
      } else ((float*)Yd)[oi] = v;
    }
  }
}

// Transposed ks=2 conv: out[n,co] = sum_ci X[par[n],ci] * W[off[n],ci,co]
__global__ __launch_bounds__(64) void k_deconv(
    const float* __restrict__ X, const int* __restrict__ par, const int* __restrict__ off,
    const void* __restrict__ P, size_t wofs, float* __restrict__ Y, int N, int CI, int CO,
    const int* __restrict__ flagp)
{
  int wbf = *flagp;
  int n = blockIdx.y;
  int co = blockIdx.x * 64 + threadIdx.x;
  if (co >= CO) return;
  const float* xr = X + (size_t)par[n] * CI;
  const size_t wp = wofs + (size_t)off[n] * CI * CO;
  float acc = 0.f;
  for (int ci = 0; ci < CI; ++ci) acc += xr[ci] * pload(P, wbf, wp + (size_t)ci * CO + co);
  Y[(size_t)n * CO + co] = acc;
}

__global__ __launch_bounds__(256) void k_bn_stats(
    const float* __restrict__ X, float* __restrict__ st, int total, int C)
{
  __shared__ float ssum[256], ssq[256];
  for (int cc = threadIdx.x; cc < C; cc += 256) { ssum[cc] = 0.f; ssq[cc] = 0.f; }
  __syncthreads();
  int stride = gridDim.x * 256;
  for (int i = blockIdx.x * 256 + threadIdx.x; i < total; i += stride) {
    float v = X[i]; int cc = i % C;
    atomicAdd(&ssum[cc], v); atomicAdd(&ssq[cc], v * v);
  }
  __syncthreads();
  for (int cc = threadIdx.x; cc < C; cc += 256) {
    atomicAdd(&st[cc], ssum[cc]);
    atomicAdd(&st[512 + cc], ssq[cc]);
  }
}

__global__ void k_bn_fin(float* st, int C, float invN)
{
  int c = blockIdx.x * blockDim.x + threadIdx.x;
  if (c < C) {
    float m = st[c] * invN;
    float v = st[512 + c] * invN - m * m;
    st[c] = m; st[512 + c] = rsqrtf(v + 1e-5f);
  }
}

__global__ __launch_bounds__(256) void k_bn_apply(
    const float* __restrict__ X, const float* __restrict__ st,
    const float* __restrict__ add, float* __restrict__ Y, int relu, int total, int C)
{
  int stride = gridDim.x * 256;
  for (int i = blockIdx.x * 256 + threadIdx.x; i < total; i += stride) {
    int cc = i % C;
    float v = (X[i] - st[cc]) * st[512 + cc];
    if (add) v += add[i];
    if (relu) v = fmaxf(v, 0.f);
    Y[i] = v;
  }
}

__global__ void k_b2f(const void* __restrict__ S, const int* __restrict__ flagp,
                      float* __restrict__ D, int n)
{
  int f = *flagp;
  int stride = gridDim.x * blockDim.x;
  for (int i = blockIdx.x * blockDim.x + threadIdx.x; i < n; i += stride)
    D[i] = pload(S, f, i);
}

__global__ void k_copycols(const float* __restrict__ S, float* __restrict__ D,
                           int N, int Cs, int Cd, int off)
{
  int total = N * Cs;
  int stride = gridDim.x * blockDim.x;
  for (int i = blockIdx.x * blockDim.x + threadIdx.x; i < total; i += stride) {
    int n = i / Cs, cc = i - n * Cs;
    D[(size_t)n * Cd + off + cc] = S[i];
  }
}

// ---------------- host orchestration ----------------

struct Ctx { hipStream_t s; const void* P; size_t po; float* st; const int* flag; };

static inline int cdiv(int a, int b) { return (a + b - 1) / b; }
static size_t takeW(Ctx& c, size_t n) { size_t o = c.po; c.po += n; return o; }

static void convop(Ctx& c, const float* X, const int* nbr, int K, int CI, int CO, float* Y, int N) {
  size_t w = takeW(c, (size_t)K * CI * CO);
  dim3 g(cdiv(N, TN), cdiv(CO, TCO));
  k_conv<<<g, 256, 0, c.s>>>(X, nbr, c.P, w, Y, 0, (size_t)-1, 0, N, K, CI, CO, c.flag);
}

static void linop(Ctx& c, const float* X, int CI, int CO, int N, void* Y, int out_dyn, bool bias, int relu) {
  size_t w = takeW(c, (size_t)CI * CO);
  size_t b = bias ? takeW(c, (size_t)CO) : (size_t)-1;
  dim3 g(cdiv(N, TN), cdiv(CO, TCO));
  k_conv<<<g, 256, 0, c.s>>>(X, (const int*)nullptr, c.P, w, Y, out_dyn, b, relu, N, 1, CI, CO, c.flag);
}

static void bnop(Ctx& c, float* X, int N, int C, const float* add, int relu, float* out) {
  hipMemsetAsync(c.st, 0, 1024 * sizeof(float), c.s);
  int total = N * C;
  int nb = (total + 255) / 256; if (nb > 1024) nb = 1024;
  k_bn_stats<<<nb, 256, 0, c.s>>>(X, c.st, total, C);
  k_bn_fin<<<1, 256, 0, c.s>>>(c.st, C, 1.0f / (float)N);
  k_bn_apply<<<nb, 256, 0, c.s>>>(X, c.st, add, out ? out : X, relu, total, C);
}

static void deconvop(Ctx& c, const float* X, const int* par, const int* off, int CI, int CO, float* Y, int N) {
  size_t w = takeW(c, (size_t)8 * CI * CO);
  dim3 g(cdiv(CO, 64), N);
  k_deconv<<<g, 64, 0, c.s>>>(X, par, off, c.P, w, Y, N, CI, CO, c.flag);
}

static void copyop(Ctx& c, const float* S, float* D, int N, int Cs, int Cd, int off) {
  int total = N * Cs;
  int nb = (total + 255) / 256; if (nb > 2048) nb = 2048;
  k_copycols<<<nb, 256, 0, c.s>>>(S, D, N, Cs, Cd, off);
}

// h = bn(conv2(relu(bn(conv1(H))))); s = H or bn(H@Wsc); OUT = relu(h + s)
static void resblock(Ctx& c, const int* nbr, int N, int CI, int CO,
                     float* H, float* A, float* B, float* Csc, float* OUT) {
  convop(c, H, nbr, 27, CI, CO, A, N);
  bnop(c, A, N, CO, nullptr, 1, nullptr);
  convop(c, A, nbr, 27, CO, CO, B, N);
  const float* S;
  if (CI == CO) S = H;
  else {
    linop(c, H, CI, CO, N, Csc, 0, false, 0);
    bnop(c, Csc, N, CO, nullptr, 0, nullptr);
    S = Csc;
  }
  bnop(c, B, N, CO, S, 1, OUT);
}

extern "C" void kernel_launch(void* const* d_in, const int* in_sizes, int n_in,
                              void* d_out, int out_size, void* d_ws, size_t ws_size,
                              hipStream_t stream)
{
  const void* x_raw = d_in[0];
  const int* nbr0 = (const int*)d_in[1];
  const int* nbr1 = (const int*)d_in[2];
  const int* nbr2 = (const int*)d_in[3];
  const int* nbr3 = (const int*)d_in[4];
  const int* nbr4 = (const int*)d_in[5];
  const int* d1 = (const int*)d_in[6];
  const int* d2 = (const int*)d_in[7];
  const int* d3 = (const int*)d_in[8];
  const int* d4 = (const int*)d_in[9];
  const int* u1p = (const int*)d_in[10]; const int* u1o = (const int*)d_in[11];
  const int* u2p = (const int*)d_in[12]; const int* u2o = (const int*)d_in[13];
  const int* u3p = (const int*)d_in[14]; const int* u3o = (const int*)d_in[15];
  const int* u4p = (const int*)d_in[16]; const int* u4o = (const int*)d_in[17];
  const void* params = d_in[18];
  (void)in_sizes; (void)n_in; (void)out_size;

  float* w = (float*)d_ws;
  size_t o = 0;
  auto alloc = [&](size_t n) { float* p = w + o; o += n; return p; };
  int* flagp = (int*)alloc(16);
  float* Xf = alloc((size_t)NP0 * 4);
  float* x0 = alloc((size_t)NP0 * 32);
  float* x1 = alloc((size_t)NP1 * 32);
  float* x2 = alloc((size_t)NP2 * 64);
  float* x3 = alloc((size_t)NP3 * 128);
  float* x4 = alloc((size_t)NP4 * 256);
  float* st = alloc(1024);
  float* U  = alloc((size_t)NP0 * 96);
  float* A  = alloc((size_t)NP0 * 96);
  float* B  = alloc((size_t)NP0 * 128);
  float* Cb = alloc((size_t)NP0 * 96);

  // Tripwire: if ws too small, emit zeros (finite wrong answer => diagnosis).
  if (ws_size < o * sizeof(float)) {
    hipMemsetAsync(d_out, 0, (size_t)out_size * 2, stream);
    return;
  }

  Ctx c{stream, params, 0, st, flagp};

  k_sniff<<<1, 256, 0, stream>>>(x_raw, flagp);
  k_b2f<<<cdiv(NP0 * 4, 256), 256, 0, stream>>>(x_raw, flagp, Xf, NP0 * 4);

  // stem
  convop(c, Xf, nbr0, 27, 4, 32, U, NP0);  bnop(c, U, NP0, 32, nullptr, 1, nullptr);
  convop(c, U, nbr0, 27, 32, 32, x0, NP0); bnop(c, x0, NP0, 32, nullptr, 1, nullptr);
  // stage1
  convop(c, x0, d1, 8, 32, 32, U, NP1); bnop(c, U, NP1, 32, nullptr, 1, nullptr);
  resblock(c, nbr1, NP1, 32, 32, U, A, B, Cb, U);
  resblock(c, nbr1, NP1, 32, 32, U, A, B, Cb, x1);
  // stage2
  convop(c, x1, d2, 8, 32, 32, U, NP2); bnop(c, U, NP2, 32, nullptr, 1, nullptr);
  resblock(c, nbr2, NP2, 32, 64, U, A, B, Cb, U);
  resblock(c, nbr2, NP2, 64, 64, U, A, B, Cb, x2);
  // stage3
  convop(c, x2, d3, 8, 64, 64, U, NP3); bnop(c, U, NP3, 64, nullptr, 1, nullptr);
  resblock(c, nbr3, NP3, 64, 128, U, A, B, Cb, U);
  resblock(c, nbr3, NP3, 128, 128, U, A, B, Cb, x3);
  // stage4
  convop(c, x3, d4, 8, 128, 128, U, NP4); bnop(c, U, NP4, 128, nullptr, 1, nullptr);
  resblock(c, nbr4, NP4, 128, 256, U, A, B, Cb, U);
  resblock(c, nbr4, NP4, 256, 256, U, A, B, Cb, x4);
  // up1
  deconvop(c, x4, u1p, u1o, 256, 256, A, NP3); bnop(c, A, NP3, 256, nullptr, 1, nullptr);
  copyop(c, A, B, NP3, 256, 384, 0); copyop(c, x3, B, NP3, 128, 384, 256);
  resblock(c, nbr3, NP3, 384, 256, B, A, U, Cb, B);
  resblock(c, nbr3, NP3, 256, 256, B, A, U, Cb, U);
  // up2
  deconvop(c, U, u2p, u2o, 256, 128, A, NP2); bnop(c, A, NP2, 128, nullptr, 1, nullptr);
  copyop(c, A, B, NP2, 128, 192, 0); copyop(c, x2, B, NP2, 64, 192, 128);
  resblock(c, nbr2, NP2, 192, 128, B, A, U, Cb, B);
  resblock(c, nbr2, NP2, 128, 128, B, A, U, Cb, U);
  // up3
  deconvop(c, U, u3p, u3o, 128, 96, A, NP1); bnop(c, A, NP1, 96, nullptr, 1, nullptr);
  copyop(c, A, B, NP1, 96, 128, 0); copyop(c, x1, B, NP1, 32, 128, 96);
  resblock(c, nbr1, NP1, 128, 96, B, A, U, Cb, B);
  resblock(c, nbr1, NP1, 96, 96, B, A, U, Cb, U);
  // up4
  deconvop(c, U, u4p, u4o, 96, 96, A, NP0); bnop(c, A, NP0, 96, nullptr, 1, nullptr);
  copyop(c, A, B, NP0, 96, 128, 0); copyop(c, x0, B, NP0, 32, 128, 96);
  resblock(c, nbr0, NP0, 128, 96, B, A, U, Cb, B);
  resblock(c, nbr0, NP0, 96, 96, B, A, U, Cb, U);
  // head
  void* out_logits = d_out;
  // feature offset depends on output dtype; compute both candidates
  // (elements are contiguous: logits [N0,19] then feat [N0,128])
  // we pass element offset and let k_conv's dynamic store path index it.
  // Simplest: two pointers per dtype; bf16 path uses bf16*, fp32 path float*.
  // k_conv indexes (size_t)r*CO+co relative to base, so base must be the
  // feat start in the right dtype. Use both and select inside via flag:
  // we instead just launch with byte-offset precomputed per dtype using a
  // union trick: pass base d_out and add element offset via r offset? No —
  // cleanest: launch twice is not needed; pass void* computed for each dtype
  // is impossible host-side. So: write feat via a dedicated out_dyn=2 mode?
  // Simpler: out_dyn stores use element offset added inside. We pass the
  // element offset via 'bofs'? No, bofs is bias. => use separate kernel arg:
  // reuse linop with Y = d_out and a column offset baked into CO indexing is
  // wrong. We instead write feat to ws then copy with dynamic kernel below.
  linop(c, U, 96, 19, NP0, out_logits, 1, true, 0);
  linop(c, U, 96, 96, NP0, A, 0, true, 1);
  linop(c, A, 96, 128, NP0, B, 0, true, 0);
  // copy feat ws->d_out at element offset N0*19 with dtype per flag
  {
    int total = NP0 * 128;
    int nb = cdiv(total, 256); if (nb > 2048) nb = 2048;
    // dedicated dynamic-store copy kernel
    extern __global__ void k_store_dyn(const float*, void*, const int*, size_t, int);
    k_store_dyn<<<nb, 256, 0, stream>>>(B, d_out, flagp, (size_t)NP0 * 19, total);
  }
}

__global__ void k_store_dyn(const float* __restrict__ S, void* __restrict__ D,
                            const int* __restrict__ flagp, size_t eofs, int n)
{
  int f = *flagp;
  int stride = gridDim.x * blockDim.x;
  for (int i = blockIdx.x * blockDim.x + threadIdx.x; i < n; i += stride) {
    float v = S[i];
    if (f) ((bf16*)D)[eofs + i] = __float2bfloat16(v);
    else ((float*)D)[eofs + i] = v;
  }
}

// Round 6
// 7031.089 us; speedup vs baseline: 4.3184x; 4.3184x over previous
//
#include <hip/hip_runtime.h>
#include <hip/hip_bf16.h>
#include <stdint.h>

typedef __hip_bfloat16 hbf;
typedef unsigned short u16;
typedef __attribute__((ext_vector_type(8))) short bfrag;   // 8 bf16 = 4 VGPRs
typedef __attribute__((ext_vector_type(4))) float f4;      // 16x16 accumulator

#define NP0 50000
#define NP1 20000
#define NP2 8000
#define NP3 3200
#define NP4 1300

static inline int cdiv(int a, int b) { return (a + b - 1) / b; }

static __device__ __forceinline__ float u2f(u16 u) { return __uint_as_float(((unsigned)u) << 16); }
static __device__ __forceinline__ u16 f2u(float f) {
  hbf h = __float2bfloat16(f);
  u16 r; __builtin_memcpy(&r, &h, 2); return r;
}
static __device__ __forceinline__ float pload(const void* P, int isbf, size_t i) {
  return isbf ? u2f(((const u16*)P)[i]) : ((const float*)P)[i];
}

// ---- dtype sniffer: bf16 wire (flag=1) vs fp32 wire (flag=0) ----
// For fp32 wire, u16[2i] is the LOW half of float i: random mantissa bits ->
// interpreting as bf16 gives huge/NaN values with probability ~1 over 2048.
__global__ void k_sniff(const void* __restrict__ xraw, int* __restrict__ flagp) {
  __shared__ float smax[256];
  const u16* u = (const u16*)xraw;
  float m = 0.f;
  for (int i = threadIdx.x; i < 2048; i += 256) {
    float v = u2f(u[2 * i]);
    if (isnan(v) || isinf(v)) m = 1e30f; else m = fmaxf(m, fabsf(v));
  }
  smax[threadIdx.x] = m;
  __syncthreads();
  for (int s = 128; s > 0; s >>= 1) {
    if (threadIdx.x < s) smax[threadIdx.x] = fmaxf(smax[threadIdx.x], smax[threadIdx.x + s]);
    __syncthreads();
  }
  if (threadIdx.x == 0) *flagp = (smax[0] < 1e4f) ? 1 : 0;
}

// ---- JIT weight prep: params[src..] -> split hi/lo 16x16x32 B-fragments ----
// chunk c enumerates [k][cb][nt][lane], 8 elems j per chunk:
//   co = nt*16 + (lane&15), ci = cb*32 + (lane>>4)*8 + j
// hi at W[c*8], lo at W[halfel + c*8]  (w = hi + lo to ~2^-18 rel)
__global__ __launch_bounds__(256) void k_prep_frag(
    const void* __restrict__ P, const int* __restrict__ flagp, u16* __restrict__ W,
    long src, long halfel, int K, int CI, int CO, int CB32, int NT16)
{
  int f = *flagp;
  long total = (long)K * CB32 * NT16 * 64;
  for (long c = (long)blockIdx.x * 256 + threadIdx.x; c < total; c += (long)gridDim.x * 256) {
    int lane = (int)(c & 63); long t = c >> 6;
    int nt = (int)(t % NT16); t /= NT16;
    int cb = (int)(t % CB32); int k = (int)(t / CB32);
    int co = nt * 16 + (lane & 15);
    int cib = cb * 32 + (lane >> 4) * 8;
    u16 hi[8], lo[8];
#pragma unroll
    for (int j = 0; j < 8; ++j) {
      int ci = cib + j; float v = 0.f;
      if (ci < CI && co < CO) v = pload(P, f, src + ((size_t)k * CI + ci) * CO + co);
      u16 h = f2u(v);
      hi[j] = h;
      lo[j] = f2u(v - u2f(h));
    }
    *(bfrag*)(W + c * 8) = *(const bfrag*)hi;
    *(bfrag*)(W + halfel + c * 8) = *(const bfrag*)lo;
  }
}

// ---- bias prep: params -> fp32 staging (exact at wire precision) ----
__global__ void k_prep_bias(const void* __restrict__ P, const int* __restrict__ flagp,
                            float* __restrict__ B, long src, int n)
{
  int f = *flagp;
  int i = blockIdx.x * 256 + threadIdx.x;
  if (i < n) B[i] = pload(P, f, src + i);
}

// ---- pad input x [N,4] -> fp32 [N,32] ----
__global__ void k_pad(const void* __restrict__ xraw, const int* __restrict__ flagp,
                      float* __restrict__ Xp, int N)
{
  int f = *flagp; int total = N * 32;
  for (int i = blockIdx.x * 256 + threadIdx.x; i < total; i += gridDim.x * 256) {
    int n = i >> 5, cc = i & 31;
    Xp[i] = (cc < 4) ? pload(xraw, f, (size_t)n * 4 + cc) : 0.f;
  }
}

// ---- split-bf16 MFMA gather-GEMM (16x16x32) ----
// Y = gatherA(fp32) @ W(fp32-as-hi+lo) ; 3 MFMAs per fragment pair:
//   AloBhi + AhiBlo + AhiBhi  (drop AloBlo ~2^-18)
template<int NT>
__global__ __launch_bounds__(256) void k_conv_mfma(
    const float* __restrict__ X, const int* __restrict__ nbr,
    const u16* __restrict__ Wp, long halfel, float* __restrict__ Y,
    const float* __restrict__ bias, int relu,
    int N, int K, int CB32, int NT16, int CO, int XS)
{
  const int lane = threadIdx.x & 63;
  const int wv = threadIdx.x >> 6;
  const int rowbase = blockIdx.x * 128 + wv * 32;
  const int ntb = blockIdx.y * NT;
  const int ml = lane & 15;
  const int quad = lane >> 4;
  f4 acc[2][NT];
#pragma unroll
  for (int i = 0; i < 2; ++i)
#pragma unroll
    for (int j = 0; j < NT; ++j) acc[i][j] = (f4)(0.f);

  for (int k = 0; k < K; ++k) {
    int idx[2];
#pragma unroll
    for (int mt = 0; mt < 2; ++mt) {
      int r = rowbase + mt * 16 + ml;
      idx[mt] = (r < N) ? (nbr ? nbr[(size_t)r * K + k] : r) : 0;
    }
    const u16* WkH = Wp + (size_t)k * CB32 * NT16 * 512;
    const u16* WkL = WkH + halfel;
    for (int cb = 0; cb < CB32; ++cb) {
      bfrag bh[NT], bl[NT];
#pragma unroll
      for (int nt = 0; nt < NT; ++nt) {
        size_t o = (((size_t)cb * NT16 + ntb + nt) * 64 + lane) * 8;
        bh[nt] = *(const bfrag*)(WkH + o);
        bl[nt] = *(const bfrag*)(WkL + o);
      }
      bfrag ahi[2], alo[2];
#pragma unroll
      for (int mt = 0; mt < 2; ++mt) {
        const float* ap = X + (size_t)idx[mt] * XS + cb * 32 + quad * 8;
        float4 q0 = *(const float4*)ap;
        float4 q1 = *(const float4*)(ap + 4);
        float av[8] = {q0.x, q0.y, q0.z, q0.w, q1.x, q1.y, q1.z, q1.w};
        u16 hi8[8], lo8[8];
#pragma unroll
        for (int j = 0; j < 8; ++j) {
          u16 hh = f2u(av[j]);
          hi8[j] = hh;
          lo8[j] = f2u(av[j] - u2f(hh));
        }
        __builtin_memcpy(&ahi[mt], hi8, 16);
        __builtin_memcpy(&alo[mt], lo8, 16);
      }
#pragma unroll
      for (int mt = 0; mt < 2; ++mt)
#pragma unroll
        for (int nt = 0; nt < NT; ++nt) {
          acc[mt][nt] = __builtin_amdgcn_mfma_f32_16x16x32_bf16(alo[mt], bh[nt], acc[mt][nt], 0, 0, 0);
          acc[mt][nt] = __builtin_amdgcn_mfma_f32_16x16x32_bf16(ahi[mt], bl[nt], acc[mt][nt], 0, 0, 0);
          acc[mt][nt] = __builtin_amdgcn_mfma_f32_16x16x32_bf16(ahi[mt], bh[nt], acc[mt][nt], 0, 0, 0);
        }
    }
  }
  // epilogue: C/D layout col=lane&15, row=quad*4+reg (m89/m91 verified)
#pragma unroll
  for (int mt = 0; mt < 2; ++mt) {
#pragma unroll
    for (int nt = 0; nt < NT; ++nt) {
      int col = (ntb + nt) * 16 + ml;
      if (col >= CO) continue;
      float bvv = bias ? bias[col] : 0.f;
#pragma unroll
      for (int reg = 0; reg < 4; ++reg) {
        int row = rowbase + mt * 16 + quad * 4 + reg;
        if (row < N) {
          float v = acc[mt][nt][reg] + bvv;
          if (relu) v = fmaxf(v, 0.f);
          Y[(size_t)row * CO + col] = v;
        }
      }
    }
  }
}

static void launch_conv(hipStream_t s, int bx, const float* X, const int* nbr,
                        const u16* W, long halfel, float* Y, const float* bias, int relu,
                        int N, int K, int CB32, int NT16, int CO, int XS)
{
  int NT = (NT16 % 6 == 0) ? 6 : ((NT16 % 4 == 0) ? 4 : 2);
  dim3 g(bx, NT16 / NT);
  if (NT == 6)      k_conv_mfma<6><<<g, 256, 0, s>>>(X, nbr, W, halfel, Y, bias, relu, N, K, CB32, NT16, CO, XS);
  else if (NT == 4) k_conv_mfma<4><<<g, 256, 0, s>>>(X, nbr, W, halfel, Y, bias, relu, N, K, CB32, NT16, CO, XS);
  else              k_conv_mfma<2><<<g, 256, 0, s>>>(X, nbr, W, halfel, Y, bias, relu, N, K, CB32, NT16, CO, XS);
}

// ---- transposed ks=2 conv: out[n] = X[par[n]] @ W[off[n]], W read at wire precision ----
__global__ __launch_bounds__(256) void k_deconv(
    const float* __restrict__ X, const int* __restrict__ par, const int* __restrict__ off,
    const void* __restrict__ P, long wofs, const int* __restrict__ flagp,
    float* __restrict__ Y, int N, int CI, int CO)
{
  int f = *flagp;
  int lane = threadIdx.x & 63, wv = threadIdx.x >> 6;
  int n = blockIdx.y * 4 + wv; if (n >= N) return;
  int co = blockIdx.x * 64 + lane; if (co >= CO) return;
  const float* xr = X + (size_t)par[n] * CI;
  size_t wbase = wofs + (size_t)off[n] * CI * CO + co;
  float acc = 0.f;
  for (int ci = 0; ci < CI; ++ci) acc += xr[ci] * pload(P, f, wbase + (size_t)ci * CO);
  Y[(size_t)n * CO + co] = acc;
}

// ---- BN (fp32) ----
__global__ __launch_bounds__(256) void k_bn_stats(
    const float* __restrict__ X, float* __restrict__ st, int total, int C)
{
  __shared__ float ssum[384], ssq[384];
  for (int c = threadIdx.x; c < C; c += 256) { ssum[c] = 0.f; ssq[c] = 0.f; }
  __syncthreads();
  int stride = gridDim.x * 256;
  for (int i = blockIdx.x * 256 + threadIdx.x; i < total; i += stride) {
    float v = X[i]; int cc = i % C;
    atomicAdd(&ssum[cc], v); atomicAdd(&ssq[cc], v * v);
  }
  __syncthreads();
  for (int c = threadIdx.x; c < C; c += 256) {
    atomicAdd(&st[c], ssum[c]); atomicAdd(&st[384 + c], ssq[c]);
  }
}

__global__ __launch_bounds__(256) void k_bn_apply(
    const float* __restrict__ X, const float* __restrict__ st, const float* __restrict__ add,
    float* __restrict__ Y, int relu, int total, int C, float invN)
{
  __shared__ float mean[384], rsig[384];
  for (int c = threadIdx.x; c < C; c += 256) {
    float mm = st[c] * invN;
    float vv = st[384 + c] * invN - mm * mm;
    mean[c] = mm; rsig[c] = rsqrtf(vv + 1e-5f);
  }
  __syncthreads();
  int stride = gridDim.x * 256;
  for (int i = blockIdx.x * 256 + threadIdx.x; i < total; i += stride) {
    int cc = i % C;
    float v = (X[i] - mean[cc]) * rsig[cc];
    if (add) v += add[i];
    if (relu) v = fmaxf(v, 0.f);
    Y[i] = v;
  }
}

__global__ void k_copycols(const float* __restrict__ S, float* __restrict__ D,
                           int N, int Cs, int Cd, int off)
{
  int total = N * Cs;
  int stride = gridDim.x * 256;
  for (int i = blockIdx.x * 256 + threadIdx.x; i < total; i += stride) {
    int n = i / Cs, cc = i - n * Cs;
    D[(size_t)n * Cd + off + cc] = S[i];
  }
}

__global__ void k_store_dyn(const float* __restrict__ S, void* __restrict__ D,
                            const int* __restrict__ flagp, size_t eofs, int n)
{
  int f = *flagp;
  int stride = gridDim.x * 256;
  for (int i = blockIdx.x * 256 + threadIdx.x; i < n; i += stride) {
    float v = S[i];
    if (f) ((u16*)D)[eofs + i] = f2u(v);
    else ((float*)D)[eofs + i] = v;
  }
}

// ---------------- host orchestration ----------------

extern "C" void kernel_launch(void* const* d_in, const int* in_sizes, int n_in,
                              void* d_out, int out_size, void* d_ws, size_t ws_size,
                              hipStream_t stream)
{
  const void* xraw = d_in[0];
  const int* nbr0 = (const int*)d_in[1];
  const int* nbr1 = (const int*)d_in[2];
  const int* nbr2 = (const int*)d_in[3];
  const int* nbr3 = (const int*)d_in[4];
  const int* nbr4 = (const int*)d_in[5];
  const int* d1 = (const int*)d_in[6];
  const int* d2 = (const int*)d_in[7];
  const int* d3 = (const int*)d_in[8];
  const int* d4 = (const int*)d_in[9];
  const int* u1p = (const int*)d_in[10]; const int* u1o = (const int*)d_in[11];
  const int* u2p = (const int*)d_in[12]; const int* u2o = (const int*)d_in[13];
  const int* u3p = (const int*)d_in[14]; const int* u3o = (const int*)d_in[15];
  const int* u4p = (const int*)d_in[16]; const int* u4o = (const int*)d_in[17];
  const void* params = d_in[18];
  (void)in_sizes; (void)n_in;

  // workspace layout (~89 MB)
  char* base = (char*)d_ws; size_t off = 0;
  auto ab = [&](size_t bytes) -> void* { void* p = base + off; off += (bytes + 63) & ~(size_t)63; return p; };
  int* flagp = (int*)ab(64);
  float* st = (float*)ab((size_t)64 * 768 * 4);
  u16* Wst = (u16*)ab((size_t)5400000 * 2);   // hi+lo frag staging (max 2x2.66M)
  float* Bstf = (float*)ab((size_t)512 * 4);  // fp32 bias staging
  float* x0 = (float*)ab((size_t)NP0 * 32 * 4);
  float* x1 = (float*)ab((size_t)NP1 * 32 * 4);
  float* x2 = (float*)ab((size_t)NP2 * 64 * 4);
  float* x3 = (float*)ab((size_t)NP3 * 128 * 4);
  float* x4 = (float*)ab((size_t)NP4 * 256 * 4);
  float* U  = (float*)ab((size_t)NP0 * 96 * 4);
  float* A  = (float*)ab((size_t)NP0 * 96 * 4);
  float* B  = (float*)ab((size_t)NP0 * 128 * 4);
  float* Xp = B;  // overlay: Xp dead before B's first use (stage1 rb t2)
  if (off > ws_size) { hipMemsetAsync(d_out, 0, (size_t)out_size * 2, stream); return; }

  long po = 0;   // param element cursor
  int bnc = 0;   // BN slot cursor

  auto prepF = [&](int K, int CI, int CO, int CB32, int NT16) -> long {
    long chunks = (long)K * CB32 * NT16 * 64;
    long halfel = chunks * 8;
    int nb = (int)((chunks + 255) / 256); if (nb > 4096) nb = 4096; if (nb < 1) nb = 1;
    k_prep_frag<<<nb, 256, 0, stream>>>(params, flagp, Wst, po, halfel, K, CI, CO, CB32, NT16);
    po += (long)K * CI * CO;
    return halfel;
  };
  auto convop = [&](const float* X, const int* nb_, int K, int CI, int CO, float* Y, int N, int XS) {
    int CB32 = cdiv(CI, 32), NT16 = cdiv(CO, 16);
    long halfel = prepF(K, CI, CO, CB32, NT16);
    launch_conv(stream, cdiv(N, 128), X, nb_, Wst, halfel, Y, nullptr, 0, N, K, CB32, NT16, CO, XS);
  };
  auto linop = [&](const float* X, int CI, int CO, float* Y, int N, bool bias, int relu) {
    int CB32 = cdiv(CI, 32), NT16 = cdiv(CO, 16);
    long halfel = prepF(1, CI, CO, CB32, NT16);
    const float* bp = nullptr;
    if (bias) {
      k_prep_bias<<<cdiv(CO, 256), 256, 0, stream>>>(params, flagp, Bstf, po, CO);
      po += CO; bp = Bstf;
    }
    launch_conv(stream, cdiv(N, 128), X, nullptr, Wst, halfel, Y, bp, relu, N, 1, CB32, NT16, CO, CI);
  };
  auto deconvop = [&](const float* X, const int* par, const int* ofv, int CI, int CO, float* Y, int N) {
    long wofs = po; po += (long)8 * CI * CO;
    dim3 g(cdiv(CO, 64), cdiv(N, 4));
    k_deconv<<<g, 256, 0, stream>>>(X, par, ofv, params, wofs, flagp, Y, N, CI, CO);
  };
  auto bnop = [&](const float* X, int N, int C, const float* add, int relu, float* out) {
    float* slot = st + (size_t)(bnc++) * 768;
    int total = N * C;
    int nb1 = cdiv(total, 2048); if (nb1 > 512) nb1 = 512; if (nb1 < 1) nb1 = 1;
    k_bn_stats<<<nb1, 256, 0, stream>>>(X, slot, total, C);
    int nb2 = cdiv(total, 1024); if (nb2 > 1024) nb2 = 1024;
    k_bn_apply<<<nb2, 256, 0, stream>>>(X, slot, add, out ? out : (float*)X, relu, total, C, 1.0f / (float)N);
  };
  auto copyop = [&](const float* S, float* D, int N, int Cs, int Cd, int o2) {
    int total = N * Cs;
    int nb3 = cdiv(total, 1024); if (nb3 > 1024) nb3 = 1024;
    k_copycols<<<nb3, 256, 0, stream>>>(S, D, N, Cs, Cd, o2);
  };
  auto storeop = [&](const float* S, size_t eo, int n) {
    int nb4 = cdiv(n, 1024); if (nb4 > 1024) nb4 = 1024;
    k_store_dyn<<<nb4, 256, 0, stream>>>(S, d_out, flagp, eo, n);
  };
  // h = bn(conv2(relu(bn(conv1(H))))); s = H or bn(H@Wsc); OUT = relu(h+s)
  auto resblock = [&](const int* nb, int N, int CI, int CO,
                      float* H, float* t1, float* t2, float* OUT) {
    convop(H, nb, 27, CI, CO, t1, N, CI);
    bnop(t1, N, CO, nullptr, 1, nullptr);
    convop(t1, nb, 27, CO, CO, t2, N, CO);
    const float* S;
    if (CI == CO) S = H;
    else { linop(H, CI, CO, t1, N, false, 0); bnop(t1, N, CO, nullptr, 0, nullptr); S = t1; }
    bnop(t2, N, CO, S, 1, OUT);
  };

  k_sniff<<<1, 256, 0, stream>>>(xraw, flagp);
  hipMemsetAsync(st, 0, (size_t)64 * 768 * 4, stream);
  k_pad<<<1024, 256, 0, stream>>>(xraw, flagp, Xp, NP0);

  // stem
  convop(Xp, nbr0, 27, 4, 32, A, NP0, 32);  bnop(A, NP0, 32, nullptr, 1, nullptr);
  convop(A, nbr0, 27, 32, 32, x0, NP0, 32); bnop(x0, NP0, 32, nullptr, 1, nullptr);
  // stage1
  convop(x0, d1, 8, 32, 32, U, NP1, 32); bnop(U, NP1, 32, nullptr, 1, nullptr);
  resblock(nbr1, NP1, 32, 32, U, A, B, U);
  resblock(nbr1, NP1, 32, 32, U, A, B, x1);
  // stage2
  convop(x1, d2, 8, 32, 32, U, NP2, 32); bnop(U, NP2, 32, nullptr, 1, nullptr);
  resblock(nbr2, NP2, 32, 64, U, A, B, U);
  resblock(nbr2, NP2, 64, 64, U, A, B, x2);
  // stage3
  convop(x2, d3, 8, 64, 64, U, NP3, 64); bnop(U, NP3, 64, nullptr, 1, nullptr);
  resblock(nbr3, NP3, 64, 128, U, A, B, U);
  resblock(nbr3, NP3, 128, 128, U, A, B, x3);
  // stage4
  convop(x3, d4, 8, 128, 128, U, NP4, 128); bnop(U, NP4, 128, nullptr, 1, nullptr);
  resblock(nbr4, NP4, 128, 256, U, A, B, U);
  resblock(nbr4, NP4, 256, 256, U, A, B, x4);
  // up1
  deconvop(x4, u1p, u1o, 256, 256, A, NP3); bnop(A, NP3, 256, nullptr, 1, nullptr);
  copyop(A, B, NP3, 256, 384, 0); copyop(x3, B, NP3, 128, 384, 256);
  resblock(nbr3, NP3, 384, 256, B, A, U, B);
  resblock(nbr3, NP3, 256, 256, B, A, U, U);
  // up2
  deconvop(U, u2p, u2o, 256, 128, A, NP2); bnop(A, NP2, 128, nullptr, 1, nullptr);
  copyop(A, B, NP2, 128, 192, 0); copyop(x2, B, NP2, 64, 192, 128);
  resblock(nbr2, NP2, 192, 128, B, A, U, B);
  resblock(nbr2, NP2, 128, 128, B, A, U, U);
  // up3
  deconvop(U, u3p, u3o, 128, 96, A, NP1); bnop(A, NP1, 96, nullptr, 1, nullptr);
  copyop(A, B, NP1, 96, 128, 0); copyop(x1, B, NP1, 32, 128, 96);
  resblock(nbr1, NP1, 128, 96, B, A, U, B);
  resblock(nbr1, NP1, 96, 96, B, A, U, U);
  // up4
  deconvop(U, u4p, u4o, 96, 96, A, NP0); bnop(A, NP0, 96, nullptr, 1, nullptr);
  copyop(A, B, NP0, 96, 128, 0); copyop(x0, B, NP0, 32, 128, 96);
  resblock(nbr0, NP0, 128, 96, B, A, U, B);
  resblock(nbr0, NP0, 96, 96, B, A, U, U);
  // head: logits -> x0 region (dead), t -> A, feat -> B
  linop(U, 96, 19, x0, NP0, true, 0);
  linop(U, 96, 96, A, NP0, true, 1);
  linop(A, 96, 128, B, NP0, true, 0);
  storeop(x0, 0, NP0 * 19);
  storeop(B, (size_t)NP0 * 19, NP0 * 128);
}